// Round 18
// baseline (250.012 us; speedup 1.0000x reference)
//
#include <hip/hip_runtime.h>
#include <math.h>

#define IDIM 2048
#define NE   64
#define TOPK 8
#define NB   16384
#define BM   32            // rows per block
#define BK   128           // k per chunk (halves barrier events vs BK=64)
#define NCH  (IDIM / BK)   // 16 chunks
#define TAU  2.5e-4f

// ws float layout: [0..63] f counts, [64..127] p sums, [128] z sum,
//                  [129] (int) flag count, [130..130+NB) (int) flagged row list
// byte WSPLIT_BYTE..: pre-split W tiles (16 tiles x (32KB hi + 32KB lo))
#define WS_CNT 129
#define WS_LIST 130
#define WSPLIT_BYTE 66560
#define WSPLIT_REQ  (WSPLIT_BYTE + NCH * 65536)

typedef __attribute__((ext_vector_type(8))) short bf16x8_t;  // 8 bf16 = 4 VGPRs
typedef __attribute__((ext_vector_type(4))) float f32x4_t;   // MFMA acc

__device__ __forceinline__ float softplusf(float v) {
    return (v > 0.f) ? (v + log1pf(expf(-v))) : log1pf(expf(v));
}
__device__ __forceinline__ double softplus_d(double v) {
    return (v > 0.0) ? (v + log1p(exp(-v))) : log1p(exp(v));
}

// deterministic RNE fp32 -> bf16 bits
__device__ __forceinline__ short f2bf(float f) {
    unsigned u = __float_as_uint(f);
    unsigned r = (u + 0x7FFFu + ((u >> 16) & 1u)) >> 16;
    return (short)r;
}
__device__ __forceinline__ float bf2f(short s) {
    return __uint_as_float(((unsigned)(unsigned short)s) << 16);
}

__global__ void init_ws_kernel(float* ws) {
    int t = threadIdx.x;
    if (t < WS_LIST) ws[t] = 0.0f;
}

__device__ __forceinline__ void split8(const float4 v0, const float4 v1,
                                       bf16x8_t& H, bf16x8_t& L) {
    float fv[8] = {v0.x, v0.y, v0.z, v0.w, v1.x, v1.y, v1.z, v1.w};
    #pragma unroll
    for (int q = 0; q < 8; ++q) {
        short hb = f2bf(fv[q]);
        short lb = f2bf(fv[q] - bf2f(hb));
        H[q] = hb; L[q] = lb;
    }
}

__device__ __forceinline__ void cvt_slot(const float4 v0, const float4 v1,
                                         char* hiP, char* loP, int off) {
    bf16x8_t H, L;
    split8(v0, v1, H, L);
    *(bf16x8_t*)(hiP + off) = H;
    *(bf16x8_t*)(loP + off) = L;
}

// ---------------- pass 0: init ws + pre-split W into swizzled LDS tile images ----------------
// tile t (64KB): hi byte (col*256 + slot*16) holds k-group (slot ^ (col&7)); lo at +32768
// (slot, kg in 0..15; XOR touches low 3 bits only)
__global__ __launch_bounds__(256) void prep_kernel(
    const float* __restrict__ Wg, const float* __restrict__ Wn,
    char* __restrict__ wsW, float* __restrict__ ws)
{
    if (blockIdx.x == 128) {             // merged init
        if (threadIdx.x < WS_LIST) ws[threadIdx.x] = 0.0f;
        return;
    }
    int g = blockIdx.x * 256 + threadIdx.x;   // 0..32767
    int t = g >> 11, i = g & 2047;            // 16 tiles x 2048 entries
    int col = i >> 4, slot = i & 15;
    int kg = slot ^ (col & 7);
    const float* src = (col < 64 ? Wg + (size_t)col * IDIM
                                 : Wn + (size_t)(col - 64) * IDIM) + t * BK + kg * 8;
    float4 v0 = *(const float4*)src;
    float4 v1 = *(const float4*)(src + 4);
    bf16x8_t H, L;
    split8(v0, v1, H, L);
    char* dst = wsW + (size_t)t * 65536;
    *(bf16x8_t*)(dst + i * 16)         = H;
    *(bf16x8_t*)(dst + 32768 + i * 16) = L;
}

// ---------------- pass 1: split-bf16 MFMA GEMM + gating + flag near-ties ----------------
// R16 structure with BK=128: 16 tiles, 32 barrier events (was 64).
// LDS (81920B): AH@0 (8K) AL@8192 (8K) WH@16384 (32K) WL@49152 (32K)
//   epilogue alias: sL f32[32][132] @0 (16896) ; sP@16896 sF@17152 sZ@17408
template<bool PRE>
__global__ __launch_bounds__(512, 4) void gate_main_kernel(
    const float* __restrict__ x, const float* __restrict__ noise,
    const float* __restrict__ Wg, const float* __restrict__ bg,
    const float* __restrict__ Wn, const char* __restrict__ wsW,
    float* __restrict__ out_w, float* __restrict__ out_i,
    float* __restrict__ ws, int listCap)
{
    __shared__ char smem[81920] __attribute__((aligned(16)));
    char* AH = smem;
    char* AL = smem + 8192;
    char* WH = smem + 16384;
    char* WL = smem + 49152;

    const int u   = threadIdx.x;
    const int w   = u >> 6;              // wave 0..7, owns cols [w*16, w*16+16)
    const int l   = u & 63;
    const int lr  = l & 15;
    const int lg4 = l >> 4;
    const int s7  = lr & 7;
    const int row0 = blockIdx.x * BM;

    // A staging: 512 threads, one (row, slot) entry each; content k-group = slot ^ (row&7)
    const int arow  = u >> 4;            // 0..31
    const int aslot = u & 15;            // 0..15
    const int akg   = aslot ^ (arow & 7);
    const float* pa = x + (size_t)(row0 + arow) * IDIM + akg * 8;
    const int aoff  = arow * 256 + aslot * 16;

    f32x4_t acc[2];
    #pragma unroll
    for (int mt = 0; mt < 2; ++mt) {
        f32x4_t z = {0.f, 0.f, 0.f, 0.f};
        acc[mt] = z;
    }

    float4 ra0, ra1;                 // A in-flight
    int4 wreg[8];                    // PRE: W in-flight (pre-split, 128B/thread)

#define LOADT(tt) { const int k0 = (tt) * BK;                                   \
    ra0 = *(const float4*)(pa + k0);                                            \
    ra1 = *(const float4*)(pa + k0 + 4);                                        \
    if constexpr (PRE) {                                                        \
        const char* s_ = wsW + (size_t)(tt) * 65536 + u * 16;                   \
        _Pragma("unroll")                                                       \
        for (int j_ = 0; j_ < 8; ++j_)                                          \
            wreg[j_] = *(const int4*)(s_ + j_ * 8192);                          \
    } }

#define FSTAGE(tt) do {                                                        \
    _Pragma("unroll")                                                          \
    for (int e_ = 0; e_ < 4; ++e_) {                                           \
        int idx_ = u + e_ * 512;                                               \
        int c_ = idx_ >> 4, sl_ = idx_ & 15;                                   \
        int kg_ = sl_ ^ (c_ & 7);                                              \
        const float* wr_ = ((c_ < 64) ? Wg + (size_t)c_ * IDIM                 \
                                      : Wn + (size_t)(c_ - 64) * IDIM)         \
                           + (tt) * BK + kg_ * 8;                              \
        float4 v0_ = *(const float4*)wr_;                                      \
        float4 v1_ = *(const float4*)(wr_ + 4);                                \
        cvt_slot(v0_, v1_, WH, WL, c_ * 256 + sl_ * 16);                       \
    }                                                                          \
} while (0)

    LOADT(0);

    for (int t = 0; t < NCH; ++t) {
        __syncthreads();                 // previous tile's LDS reads complete
        cvt_slot(ra0, ra1, AH, AL, aoff);
        if constexpr (PRE) {
            #pragma unroll
            for (int j = 0; j < 8; ++j)
                *(int4*)((j < 4 ? WH : WL) + (j & 3) * 8192 + u * 16) = wreg[j];
        } else {
            FSTAGE(t);
        }
        if (t + 1 < NCH) LOADT(t + 1);   // next-tile loads land during compute
        __syncthreads();                 // staging visible

        #pragma unroll
        for (int ks = 0; ks < 4; ++ks) {
            const int so = (((ks * 4 + lg4) ^ s7) << 4);
            bf16x8_t ah[2], al_[2], bh, bl;
            #pragma unroll
            for (int mt = 0; mt < 2; ++mt) {
                const int o = (mt * 16 + lr) * 256 + so;
                ah[mt]  = *(const bf16x8_t*)(AH + o);
                al_[mt] = *(const bf16x8_t*)(AL + o);
            }
            {
                const int o = (w * 16 + lr) * 256 + so;
                bh = *(const bf16x8_t*)(WH + o);
                bl = *(const bf16x8_t*)(WL + o);
            }
            #pragma unroll
            for (int mt = 0; mt < 2; ++mt) {
                acc[mt] = __builtin_amdgcn_mfma_f32_16x16x32_bf16(ah[mt],  bh, acc[mt], 0, 0, 0);
                acc[mt] = __builtin_amdgcn_mfma_f32_16x16x32_bf16(ah[mt],  bl, acc[mt], 0, 0, 0);
                acc[mt] = __builtin_amdgcn_mfma_f32_16x16x32_bf16(al_[mt], bh, acc[mt], 0, 0, 0);
            }
        }
    }
    __syncthreads();   // staging dead; safe to alias

    // ---- epilogue: acc -> sL[32][132]; init reduction cells (aliased region) ----
    float* sL = (float*)smem;
    float* sP = (float*)(smem + 16896);
    float* sF = (float*)(smem + 17152);
    float* sZ = (float*)(smem + 17408);
    if (u < NE) { sP[u] = 0.f; sF[u] = 0.f; }
    if (u == 0) sZ[0] = 0.f;
    #pragma unroll
    for (int mt = 0; mt < 2; ++mt)
        #pragma unroll
        for (int r = 0; r < 4; ++r)
            sL[(mt * 16 + lg4 * 4 + r) * 132 + (w * 16 + lr)] = acc[mt][r];
    __syncthreads();

    // ---- gating: 8 waves x 4 rows, lane = expert ----
    float pacc = 0.f, zacc = 0.f;
    #pragma unroll 1
    for (int rr = 0; rr < 4; ++rr) {
        const int r = w * 4 + rr;
        const int grow = row0 + r;
        float lg   = sL[r * 132 + l] + bg[l];
        float npre = sL[r * 132 + 64 + l];
        float vcur = fmaf(noise[(size_t)grow * NE + l], softplusf(npre), lg);

        float tkv[9]; int tki[9];
        #pragma unroll
        for (int k = 0; k < 9; ++k) {
            float mv = vcur; int mi = l;
            #pragma unroll
            for (int o = 32; o > 0; o >>= 1) {
                float ov = __shfl_xor(mv, o);
                int   oi = __shfl_xor(mi, o);
                if (ov > mv || (ov == mv && oi < mi)) { mv = ov; mi = oi; }
            }
            tkv[k] = mv; tki[k] = mi;
            if (l == mi) vcur = -1e30f;
        }

        float m0 = tkv[0], s = 0.f, wk[TOPK];
        #pragma unroll
        for (int k = 0; k < TOPK; ++k) { wk[k] = expf(tkv[k] - m0); s += wk[k]; }
        float inv = 1.f / s;
        float myw = 0.f; int myi = 0;
        #pragma unroll
        for (int k = 0; k < TOPK; ++k)
            if (l == k) { myw = wk[k] * inv; myi = tki[k]; }
        if (l < TOPK) {
            out_w[(size_t)grow * TOPK + l] = myw;
            out_i[(size_t)grow * TOPK + l] = (float)myi;
        }

        if (l == 0) {
            atomicAdd(&sF[tki[0]], 1.f);
            float ming = 1e30f;
            #pragma unroll
            for (int k = 0; k < 8; ++k) ming = fminf(ming, tkv[k] - tkv[k + 1]);
            if (ming < TAU) {
                int slot = atomicAdd((int*)&ws[WS_CNT], 1);
                if (slot < listCap) ((int*)ws)[WS_LIST + slot] = grow;
            }
        }

        float rm = lg;
        #pragma unroll
        for (int o = 32; o > 0; o >>= 1) rm = fmaxf(rm, __shfl_xor(rm, o));
        float pe = expf(lg - rm);
        float ssum = pe;
        #pragma unroll
        for (int o = 32; o > 0; o >>= 1) ssum += __shfl_xor(ssum, o);
        pacc += pe / ssum;
        if (l == 0) { float lse = rm + logf(ssum); zacc += lse * lse; }
    }

    atomicAdd(&sP[l], pacc);
    if (l == 0) atomicAdd(sZ, zacc);
    __syncthreads();
    if (u < NE) {
        atomicAdd(&ws[u],      sF[u]);
        atomicAdd(&ws[NE + u], sP[u]);
    }
    if (u == 0) atomicAdd(&ws[2 * NE], sZ[0]);
}

// ---------------- pass 2: finalize scalars (block 0) + fp64 recheck, 2 rows/block ----------------
__global__ __launch_bounds__(512) void recheck_finalize_kernel(
    const float* __restrict__ x, const float* __restrict__ noise,
    const float* __restrict__ Wg, const float* __restrict__ bg,
    const float* __restrict__ Wn,
    float* __restrict__ out_w, float* __restrict__ out_i, float* __restrict__ out_s,
    const float* __restrict__ ws, int listCap)
{
    __shared__ double sRed[1024];        // [512 threads][2 rows]
    const int t = threadIdx.x;

    if (blockIdx.x == 0 && t < 64) {     // finalize scalars (wave 0, no barriers)
        float v = (ws[t] / (float)NB) * (ws[NE + t] / (float)NB);
        #pragma unroll
        for (int o = 32; o > 0; o >>= 1) v += __shfl_down(v, o);
        if (t == 0) {
            out_s[0] = (float)NE * v;
            out_s[1] = ws[2 * NE] / (float)NB;
        }
    }

    const int* wsi = (const int*)ws;
    int cnt = wsi[WS_CNT];
    if (cnt > listCap) cnt = listCap;
    if (cnt <= 0) return;

    const int slot = t & 127;            // 0..63: Wg expert; 64..127: Wn expert-64
    const int q4   = t >> 7;             // K quarter: [q4*512, +512)
    const float* wrb = ((slot < 64) ? (Wg + (size_t)slot * IDIM)
                                    : (Wn + (size_t)(slot - 64) * IDIM)) + q4 * 512;

    const int npair = (cnt + 1) >> 1;
    for (int bi = blockIdx.x; bi < npair; bi += gridDim.x) {
        const int i1 = 2 * bi + 1;
        const int r0 = wsi[WS_LIST + 2 * bi];
        const int r1 = wsi[WS_LIST + (i1 < cnt ? i1 : cnt - 1)];
        const float* x0 = x + (size_t)r0 * IDIM + q4 * 512;
        const float* x1 = x + (size_t)r1 * IDIM + q4 * 512;

        double a0 = 0.0, a1 = 0.0;
        #pragma unroll 4
        for (int k = 0; k < 512; k += 4) {
            float4 wv  = *(const float4*)(wrb + k);
            float4 xv0 = *(const float4*)(x0 + k);
            float4 xv1 = *(const float4*)(x1 + k);
            a0 = fma((double)xv0.x, (double)wv.x, a0);
            a1 = fma((double)xv1.x, (double)wv.x, a1);
            a0 = fma((double)xv0.y, (double)wv.y, a0);
            a1 = fma((double)xv1.y, (double)wv.y, a1);
            a0 = fma((double)xv0.z, (double)wv.z, a0);
            a1 = fma((double)xv1.z, (double)wv.z, a1);
            a0 = fma((double)xv0.w, (double)wv.w, a0);
            a1 = fma((double)xv1.w, (double)wv.w, a1);
        }
        sRed[t * 2]     = a0;
        sRed[t * 2 + 1] = a1;
        __syncthreads();
        if (t < 128) {
            #pragma unroll
            for (int i = 0; i < 2; ++i)
                sRed[t * 2 + i] = sRed[t * 2 + i] + sRed[(t + 128) * 2 + i]
                                + sRed[(t + 256) * 2 + i] + sRed[(t + 384) * 2 + i];
        }
        __syncthreads();

        if (t < 64) {
            const int lane = t;
            const double bgl = (double)bg[lane];
            #pragma unroll 1
            for (int i = 0; i < 2; ++i) {
                const int row = i ? r1 : r0;
                double g = sRed[lane * 2 + i];
                double n = sRed[(64 + lane) * 2 + i];
                double lgd = g + bgl;
                double nz = (double)noise[(size_t)row * NE + lane];
                double vcur = fma(nz, softplus_d(n), lgd);

                double tkv[TOPK]; int tki[TOPK];
                #pragma unroll
                for (int k = 0; k < TOPK; ++k) {
                    double mv = vcur; int mi = lane;
                    #pragma unroll
                    for (int o = 32; o > 0; o >>= 1) {
                        double ov = __shfl_xor(mv, o);
                        int    oi = __shfl_xor(mi, o);
                        if (ov > mv || (ov == mv && oi < mi)) { mv = ov; mi = oi; }
                    }
                    tkv[k] = mv; tki[k] = mi;
                    if (lane == mi) vcur = -1e300;
                }
                double m0 = tkv[0], s = 0.0, wk[TOPK];
                #pragma unroll
                for (int k = 0; k < TOPK; ++k) { wk[k] = exp(tkv[k] - m0); s += wk[k]; }
                double inv = 1.0 / s;
                float myw = 0.f; int myi = 0;
                #pragma unroll
                for (int k = 0; k < TOPK; ++k)
                    if (lane == k) { myw = (float)(wk[k] * inv); myi = tki[k]; }
                if (lane < TOPK) {
                    out_w[(size_t)row * TOPK + lane] = myw;
                    out_i[(size_t)row * TOPK + lane] = (float)myi;
                }
            }
        }
        __syncthreads();   // sRed reuse safe
    }
}

extern "C" void kernel_launch(void* const* d_in, const int* in_sizes, int n_in,
                              void* d_out, int out_size, void* d_ws, size_t ws_size,
                              hipStream_t stream) {
    const float* x     = (const float*)d_in[0];
    const float* noise = (const float*)d_in[1];
    const float* Wg    = (const float*)d_in[2];
    const float* bg    = (const float*)d_in[3];
    const float* Wn    = (const float*)d_in[4];
    float* out = (float*)d_out;
    float* ws  = (float*)d_ws;
    char*  wsW = (char*)d_ws + WSPLIT_BYTE;

    long cap = (long)(ws_size / 4) - WS_LIST;
    int listCap = (int)(cap < 0 ? 0 : (cap > NB ? NB : cap));
    const bool pre = ws_size >= (size_t)WSPLIT_REQ;

    if (pre) {
        hipLaunchKernelGGL(prep_kernel, dim3(129), dim3(256), 0, stream, Wg, Wn, wsW, ws);
        hipLaunchKernelGGL(gate_main_kernel<true>, dim3(NB / BM), dim3(512), 0, stream,
                           x, noise, Wg, bg, Wn, wsW,
                           out, out + (size_t)NB * TOPK, ws, listCap);
    } else {
        hipLaunchKernelGGL(init_ws_kernel, dim3(1), dim3(256), 0, stream, ws);
        hipLaunchKernelGGL(gate_main_kernel<false>, dim3(NB / BM), dim3(512), 0, stream,
                           x, noise, Wg, bg, Wn, wsW,
                           out, out + (size_t)NB * TOPK, ws, listCap);
    }
    hipLaunchKernelGGL(recheck_finalize_kernel, dim3(1024), dim3(512), 0, stream,
                       x, noise, Wg, bg, Wn,
                       out, out + (size_t)NB * TOPK, out + 2 * (size_t)NB * TOPK,
                       ws, listCap);
}

// Round 19
// 208.542 us; speedup vs baseline: 1.1989x; 1.1989x over previous
//
#include <hip/hip_runtime.h>
#include <math.h>

#define IDIM 2048
#define NE   64
#define TOPK 8
#define NB   16384
#define BM   32            // rows per block
#define BK   64            // k per chunk
#define NCH  (IDIM / BK)   // 32 chunks (monolithic path)
#define KH   1024          // K half (split path)
#define NCHH 16            // tiles per half
#define TAU  2.5e-4f

// ws float layout: [0..63] f counts, [64..127] p sums, [128] z sum,
//                  [129] (int) flag count, [130..130+NB) (int) flagged row list
// byte WSPLIT_BYTE..: pre-split W tiles (32 tiles x (16KB hi + 16KB lo))
// byte PART0/PART1: fp32 partial logits [NB][128] per K-half (split path)
#define WS_CNT 129
#define WS_LIST 130
#define WSPLIT_BYTE 66560
#define WSPLIT_REQ  (WSPLIT_BYTE + NCH * 32768)
#define PART0_BYTE  (WSPLIT_BYTE + NCH * 32768)
#define PART1_BYTE  (PART0_BYTE + (size_t)NB * 128 * 4)
#define SPLIT_REQ   (PART1_BYTE + (size_t)NB * 128 * 4)

typedef __attribute__((ext_vector_type(8))) short bf16x8_t;  // 8 bf16 = 4 VGPRs
typedef __attribute__((ext_vector_type(4))) float f32x4_t;   // MFMA acc

__device__ __forceinline__ float softplusf(float v) {
    return (v > 0.f) ? (v + log1pf(expf(-v))) : log1pf(expf(v));
}
__device__ __forceinline__ double softplus_d(double v) {
    return (v > 0.0) ? (v + log1p(exp(-v))) : log1p(exp(v));
}

// deterministic RNE fp32 -> bf16 bits
__device__ __forceinline__ short f2bf(float f) {
    unsigned u = __float_as_uint(f);
    unsigned r = (u + 0x7FFFu + ((u >> 16) & 1u)) >> 16;
    return (short)r;
}
__device__ __forceinline__ float bf2f(short s) {
    return __uint_as_float(((unsigned)(unsigned short)s) << 16);
}

__global__ void init_ws_kernel(float* ws) {
    int t = threadIdx.x;
    if (t < WS_LIST) ws[t] = 0.0f;
}

__device__ __forceinline__ void split8(const float4 v0, const float4 v1,
                                       bf16x8_t& H, bf16x8_t& L) {
    float fv[8] = {v0.x, v0.y, v0.z, v0.w, v1.x, v1.y, v1.z, v1.w};
    #pragma unroll
    for (int q = 0; q < 8; ++q) {
        short hb = f2bf(fv[q]);
        short lb = f2bf(fv[q] - bf2f(hb));
        H[q] = hb; L[q] = lb;
    }
}

__device__ __forceinline__ void cvt_slot(const float4 v0, const float4 v1,
                                         char* hiP, char* loP, int off) {
    bf16x8_t H, L;
    split8(v0, v1, H, L);
    *(bf16x8_t*)(hiP + off) = H;
    *(bf16x8_t*)(loP + off) = L;
}

// ---------------- pass 0: init ws + pre-split W into swizzled LDS tile images ----------------
__global__ __launch_bounds__(256) void prep_kernel(
    const float* __restrict__ Wg, const float* __restrict__ Wn,
    char* __restrict__ wsW, float* __restrict__ ws)
{
    if (blockIdx.x == 128) {             // merged init
        if (threadIdx.x < WS_LIST) ws[threadIdx.x] = 0.0f;
        return;
    }
    int g = blockIdx.x * 256 + threadIdx.x;   // 0..32767
    int t = g >> 10, i = g & 1023;
    int row = i >> 3, wslot = i & 7;
    int kslot = wslot ^ (row & 7);
    const float* src = (row < 64 ? Wg + (size_t)row * IDIM
                                 : Wn + (size_t)(row - 64) * IDIM) + t * BK + kslot * 8;
    float4 v0 = *(const float4*)src;
    float4 v1 = *(const float4*)(src + 4);
    bf16x8_t H, L;
    split8(v0, v1, H, L);
    char* dst = wsW + (size_t)t * 32768;
    *(bf16x8_t*)(dst + i * 16)         = H;
    *(bf16x8_t*)(dst + 16384 + i * 16) = L;
}

// ---------------- pass 1a (split): half-K GEMM -> fp32 partials ----------------
// LDS exactly 40960B -> 4 blocks/CU: AH@0 AL@4096 BH@8192 BL@24576
__global__ __launch_bounds__(512, 4) void gemm_half_kernel(
    const float* __restrict__ x, const char* __restrict__ wsW,
    float* __restrict__ part0, float* __restrict__ part1)
{
    __shared__ char smem[40960] __attribute__((aligned(16)));
    char* AH = smem;
    char* AL = smem + 4096;
    char* BH = smem + 8192;
    char* BL = smem + 24576;

    const int u   = threadIdx.x;
    const int w   = u >> 6;
    const int l   = u & 63;
    const int lr  = l & 15;
    const int lg4 = l >> 4;
    const int s7  = lr & 7;
    const int half = blockIdx.x & 1;
    const int row0 = (blockIdx.x >> 1) * BM;
    float* pb = half ? part1 : part0;

    const int ar  = (u >> 3) & 31;
    const int ac  = u & 7;
    const int aoff = ar * 128 + (((ac ^ (ar & 7)) & 7) << 4);
    const float* pa = x + (size_t)(row0 + ar) * IDIM + half * KH + ac * 8;

    f32x4_t acc[2];
    #pragma unroll
    for (int mt = 0; mt < 2; ++mt) {
        f32x4_t z = {0.f, 0.f, 0.f, 0.f};
        acc[mt] = z;
    }

    float4 ra0, ra1;
    int4 w0, w1, w2, w3;

#define HLOADT(tt) { const int k0 = (tt) * BK;                                  \
    if (u < 256) { ra0 = *(const float4*)(pa + k0);                             \
                   ra1 = *(const float4*)(pa + k0 + 4); }                       \
    const char* s_ = wsW + (size_t)(half * NCHH + (tt)) * 32768 + u * 16;       \
    w0 = *(const int4*)(s_);          w1 = *(const int4*)(s_ + 8192);           \
    w2 = *(const int4*)(s_ + 16384);  w3 = *(const int4*)(s_ + 24576); }

    HLOADT(0);

    for (int t = 0; t < NCHH; ++t) {
        __syncthreads();
        if (u < 256) cvt_slot(ra0, ra1, AH, AL, aoff);
        *(int4*)(BH + u * 16)        = w0;
        *(int4*)(BH + 8192 + u * 16) = w1;
        *(int4*)(BL + u * 16)        = w2;
        *(int4*)(BL + 8192 + u * 16) = w3;
        if (t + 1 < NCHH) HLOADT(t + 1);
        __syncthreads();

        #pragma unroll
        for (int ks = 0; ks < 2; ++ks) {
            const int so = (((ks * 4 + lg4) ^ s7) << 4);
            bf16x8_t ah[2], al_[2], bh, bl;
            #pragma unroll
            for (int mt = 0; mt < 2; ++mt) {
                const int o = (mt * 16 + lr) * 128 + so;
                ah[mt]  = *(const bf16x8_t*)(AH + o);
                al_[mt] = *(const bf16x8_t*)(AL + o);
            }
            {
                const int o = (w * 16 + lr) * 128 + so;
                bh = *(const bf16x8_t*)(BH + o);
                bl = *(const bf16x8_t*)(BL + o);
            }
            #pragma unroll
            for (int mt = 0; mt < 2; ++mt) {
                acc[mt] = __builtin_amdgcn_mfma_f32_16x16x32_bf16(ah[mt],  bh, acc[mt], 0, 0, 0);
                acc[mt] = __builtin_amdgcn_mfma_f32_16x16x32_bf16(ah[mt],  bl, acc[mt], 0, 0, 0);
                acc[mt] = __builtin_amdgcn_mfma_f32_16x16x32_bf16(al_[mt], bh, acc[mt], 0, 0, 0);
            }
        }
    }

    // ---- store partials (C/D: col=lane&15, row=(lane>>4)*4+reg) ----
    #pragma unroll
    for (int mt = 0; mt < 2; ++mt)
        #pragma unroll
        for (int r = 0; r < 4; ++r)
            pb[(size_t)(row0 + mt * 16 + lg4 * 4 + r) * 128 + (w * 16 + lr)] = acc[mt][r];
}

// ---------------- pass 1b (split): gating from partials ----------------
__global__ __launch_bounds__(512) void gating_kernel(
    const float* __restrict__ part0, const float* __restrict__ part1,
    const float* __restrict__ noise, const float* __restrict__ bg,
    float* __restrict__ out_w, float* __restrict__ out_i,
    float* __restrict__ ws, int listCap)
{
    __shared__ float sP[NE];
    __shared__ float sF[NE];
    __shared__ float sZ[1];
    const int u = threadIdx.x;
    const int w = u >> 6, l = u & 63;
    const int row0 = blockIdx.x * 128;

    if (u < NE) { sP[u] = 0.f; sF[u] = 0.f; }
    if (u == 0) sZ[0] = 0.f;
    __syncthreads();

    float pacc = 0.f, zacc = 0.f;
    #pragma unroll 1
    for (int rr = 0; rr < 16; ++rr) {
        const int grow = row0 + w * 16 + rr;
        float lg   = part0[(size_t)grow * 128 + l] + part1[(size_t)grow * 128 + l] + bg[l];
        float npre = part0[(size_t)grow * 128 + 64 + l] + part1[(size_t)grow * 128 + 64 + l];
        float vcur = fmaf(noise[(size_t)grow * NE + l], softplusf(npre), lg);

        float tkv[9]; int tki[9];
        #pragma unroll
        for (int k = 0; k < 9; ++k) {
            float mv = vcur; int mi = l;
            #pragma unroll
            for (int o = 32; o > 0; o >>= 1) {
                float ov = __shfl_xor(mv, o);
                int   oi = __shfl_xor(mi, o);
                if (ov > mv || (ov == mv && oi < mi)) { mv = ov; mi = oi; }
            }
            tkv[k] = mv; tki[k] = mi;
            if (l == mi) vcur = -1e30f;
        }

        float m0 = tkv[0], s = 0.f, wk[TOPK];
        #pragma unroll
        for (int k = 0; k < TOPK; ++k) { wk[k] = expf(tkv[k] - m0); s += wk[k]; }
        float inv = 1.f / s;
        float myw = 0.f; int myi = 0;
        #pragma unroll
        for (int k = 0; k < TOPK; ++k)
            if (l == k) { myw = wk[k] * inv; myi = tki[k]; }
        if (l < TOPK) {
            out_w[(size_t)grow * TOPK + l] = myw;
            out_i[(size_t)grow * TOPK + l] = (float)myi;
        }

        if (l == 0) {
            atomicAdd(&sF[tki[0]], 1.f);
            float ming = 1e30f;
            #pragma unroll
            for (int k = 0; k < 8; ++k) ming = fminf(ming, tkv[k] - tkv[k + 1]);
            if (ming < TAU) {
                int slot = atomicAdd((int*)&ws[WS_CNT], 1);
                if (slot < listCap) ((int*)ws)[WS_LIST + slot] = grow;
            }
        }

        float rm = lg;
        #pragma unroll
        for (int o = 32; o > 0; o >>= 1) rm = fmaxf(rm, __shfl_xor(rm, o));
        float pe = expf(lg - rm);
        float ssum = pe;
        #pragma unroll
        for (int o = 32; o > 0; o >>= 1) ssum += __shfl_xor(ssum, o);
        pacc += pe / ssum;
        if (l == 0) { float lse = rm + logf(ssum); zacc += lse * lse; }
    }

    atomicAdd(&sP[l], pacc);
    if (l == 0) atomicAdd(sZ, zacc);
    __syncthreads();
    if (u < NE) {
        atomicAdd(&ws[u],      sF[u]);
        atomicAdd(&ws[NE + u], sP[u]);
    }
    if (u == 0) atomicAdd(&ws[2 * NE], sZ[0]);
}

// ---------------- pass 1 (fallback): R16 monolithic GEMM + gating ----------------
template<bool PRE>
__global__ __launch_bounds__(512, 4) void gate_main_kernel(
    const float* __restrict__ x, const float* __restrict__ noise,
    const float* __restrict__ Wg, const float* __restrict__ bg,
    const float* __restrict__ Wn, const char* __restrict__ wsW,
    float* __restrict__ out_w, float* __restrict__ out_i,
    float* __restrict__ ws, int listCap)
{
    __shared__ char smem[41488] __attribute__((aligned(16)));
    char* AH = smem;
    char* AL = smem + 4096;
    char* BH = smem + 8192;
    char* BL = smem + 24576;
    float* sP = (float*)(smem + 40960);
    float* sF = (float*)(smem + 41216);
    float* sZ = (float*)(smem + 41472);
    float* sL = (float*)smem;

    const int u   = threadIdx.x;
    const int w   = u >> 6;
    const int l   = u & 63;
    const int lr  = l & 15;
    const int lg4 = l >> 4;
    const int s7  = lr & 7;
    const int row0 = blockIdx.x * BM;

    if (u < NE) { sP[u] = 0.f; sF[u] = 0.f; }
    if (u == 0) sZ[0] = 0.f;

    const int ar  = (u >> 3) & 31;
    const int ac  = u & 7;
    const int aoff = ar * 128 + (((ac ^ (ar & 7)) & 7) << 4);
    const float* pa = x + (size_t)(row0 + ar) * IDIM + ac * 8;

    const int br  = u >> 3;
    const float* pg = Wg + (size_t)br * IDIM + ac * 8;
    const float* pn = Wn + (size_t)br * IDIM + ac * 8;
    const int woff = br * 128 + ((ac ^ (br & 7)) << 4);

    f32x4_t acc[2];
    #pragma unroll
    for (int mt = 0; mt < 2; ++mt) {
        f32x4_t z = {0.f, 0.f, 0.f, 0.f};
        acc[mt] = z;
    }

    float4 ra0, ra1;
    int4 w0, w1, w2, w3;
    float4 g0, g1, n0, n1;

#define LOADT(tt) { const int k0 = (tt) * BK;                                   \
    if (u < 256) { ra0 = *(const float4*)(pa + k0);                             \
                   ra1 = *(const float4*)(pa + k0 + 4); }                       \
    if constexpr (PRE) {                                                        \
        const char* s_ = wsW + (size_t)(tt) * 32768 + u * 16;                   \
        w0 = *(const int4*)(s_);          w1 = *(const int4*)(s_ + 8192);       \
        w2 = *(const int4*)(s_ + 16384);  w3 = *(const int4*)(s_ + 24576);      \
    } else {                                                                    \
        g0 = *(const float4*)(pg + k0);   g1 = *(const float4*)(pg + k0 + 4);   \
        n0 = *(const float4*)(pn + k0);   n1 = *(const float4*)(pn + k0 + 4);   \
    } }

    LOADT(0);

    for (int t = 0; t < NCH; ++t) {
        __syncthreads();
        if (u < 256) cvt_slot(ra0, ra1, AH, AL, aoff);
        if constexpr (PRE) {
            *(int4*)(BH + u * 16)        = w0;
            *(int4*)(BH + 8192 + u * 16) = w1;
            *(int4*)(BL + u * 16)        = w2;
            *(int4*)(BL + 8192 + u * 16) = w3;
        } else {
            cvt_slot(g0, g1, BH, BL, woff);
            cvt_slot(n0, n1, BH, BL, woff + 8192);
        }
        if (t + 1 < NCH) LOADT(t + 1);
        __syncthreads();

        #pragma unroll
        for (int ks = 0; ks < 2; ++ks) {
            const int so = (((ks * 4 + lg4) ^ s7) << 4);
            bf16x8_t ah[2], al_[2], bh, bl;
            #pragma unroll
            for (int mt = 0; mt < 2; ++mt) {
                const int o = (mt * 16 + lr) * 128 + so;
                ah[mt]  = *(const bf16x8_t*)(AH + o);
                al_[mt] = *(const bf16x8_t*)(AL + o);
            }
            {
                const int o = (w * 16 + lr) * 128 + so;
                bh = *(const bf16x8_t*)(BH + o);
                bl = *(const bf16x8_t*)(BL + o);
            }
            #pragma unroll
            for (int mt = 0; mt < 2; ++mt) {
                acc[mt] = __builtin_amdgcn_mfma_f32_16x16x32_bf16(ah[mt],  bh, acc[mt], 0, 0, 0);
                acc[mt] = __builtin_amdgcn_mfma_f32_16x16x32_bf16(ah[mt],  bl, acc[mt], 0, 0, 0);
                acc[mt] = __builtin_amdgcn_mfma_f32_16x16x32_bf16(al_[mt], bh, acc[mt], 0, 0, 0);
            }
        }
    }
    __syncthreads();

    #pragma unroll
    for (int mt = 0; mt < 2; ++mt)
        #pragma unroll
        for (int r = 0; r < 4; ++r)
            sL[(mt * 16 + lg4 * 4 + r) * 132 + (w * 16 + lr)] = acc[mt][r];
    __syncthreads();

    float pacc = 0.f, zacc = 0.f;
    #pragma unroll 1
    for (int rr = 0; rr < 4; ++rr) {
        const int r = w * 4 + rr;
        const int grow = row0 + r;
        float lg   = sL[r * 132 + l] + bg[l];
        float npre = sL[r * 132 + 64 + l];
        float vcur = fmaf(noise[(size_t)grow * NE + l], softplusf(npre), lg);

        float tkv[9]; int tki[9];
        #pragma unroll
        for (int k = 0; k < 9; ++k) {
            float mv = vcur; int mi = l;
            #pragma unroll
            for (int o = 32; o > 0; o >>= 1) {
                float ov = __shfl_xor(mv, o);
                int   oi = __shfl_xor(mi, o);
                if (ov > mv || (ov == mv && oi < mi)) { mv = ov; mi = oi; }
            }
            tkv[k] = mv; tki[k] = mi;
            if (l == mi) vcur = -1e30f;
        }

        float m0 = tkv[0], s = 0.f, wk[TOPK];
        #pragma unroll
        for (int k = 0; k < TOPK; ++k) { wk[k] = expf(tkv[k] - m0); s += wk[k]; }
        float inv = 1.f / s;
        float myw = 0.f; int myi = 0;
        #pragma unroll
        for (int k = 0; k < TOPK; ++k)
            if (l == k) { myw = wk[k] * inv; myi = tki[k]; }
        if (l < TOPK) {
            out_w[(size_t)grow * TOPK + l] = myw;
            out_i[(size_t)grow * TOPK + l] = (float)myi;
        }

        if (l == 0) {
            atomicAdd(&sF[tki[0]], 1.f);
            float ming = 1e30f;
            #pragma unroll
            for (int k = 0; k < 8; ++k) ming = fminf(ming, tkv[k] - tkv[k + 1]);
            if (ming < TAU) {
                int slot = atomicAdd((int*)&ws[WS_CNT], 1);
                if (slot < listCap) ((int*)ws)[WS_LIST + slot] = grow;
            }
        }

        float rm = lg;
        #pragma unroll
        for (int o = 32; o > 0; o >>= 1) rm = fmaxf(rm, __shfl_xor(rm, o));
        float pe = expf(lg - rm);
        float ssum = pe;
        #pragma unroll
        for (int o = 32; o > 0; o >>= 1) ssum += __shfl_xor(ssum, o);
        pacc += pe / ssum;
        if (l == 0) { float lse = rm + logf(ssum); zacc += lse * lse; }
    }

    atomicAdd(&sP[l], pacc);
    if (l == 0) atomicAdd(sZ, zacc);
    __syncthreads();
    if (u < NE) {
        atomicAdd(&ws[u],      sF[u]);
        atomicAdd(&ws[NE + u], sP[u]);
    }
    if (u == 0) atomicAdd(&ws[2 * NE], sZ[0]);
}

// ---------------- pass 2: finalize scalars (block 0) + fp64 recheck, 2 rows/block ----------------
__global__ __launch_bounds__(512) void recheck_finalize_kernel(
    const float* __restrict__ x, const float* __restrict__ noise,
    const float* __restrict__ Wg, const float* __restrict__ bg,
    const float* __restrict__ Wn,
    float* __restrict__ out_w, float* __restrict__ out_i, float* __restrict__ out_s,
    const float* __restrict__ ws, int listCap)
{
    __shared__ double sRed[1024];
    const int t = threadIdx.x;

    if (blockIdx.x == 0 && t < 64) {
        float v = (ws[t] / (float)NB) * (ws[NE + t] / (float)NB);
        #pragma unroll
        for (int o = 32; o > 0; o >>= 1) v += __shfl_down(v, o);
        if (t == 0) {
            out_s[0] = (float)NE * v;
            out_s[1] = ws[2 * NE] / (float)NB;
        }
    }

    const int* wsi = (const int*)ws;
    int cnt = wsi[WS_CNT];
    if (cnt > listCap) cnt = listCap;
    if (cnt <= 0) return;

    const int slot = t & 127;
    const int q4   = t >> 7;
    const float* wrb = ((slot < 64) ? (Wg + (size_t)slot * IDIM)
                                    : (Wn + (size_t)(slot - 64) * IDIM)) + q4 * 512;

    const int npair = (cnt + 1) >> 1;
    for (int bi = blockIdx.x; bi < npair; bi += gridDim.x) {
        const int i1 = 2 * bi + 1;
        const int r0 = wsi[WS_LIST + 2 * bi];
        const int r1 = wsi[WS_LIST + (i1 < cnt ? i1 : cnt - 1)];
        const float* x0 = x + (size_t)r0 * IDIM + q4 * 512;
        const float* x1 = x + (size_t)r1 * IDIM + q4 * 512;

        double a0 = 0.0, a1 = 0.0;
        #pragma unroll 4
        for (int k = 0; k < 512; k += 4) {
            float4 wv  = *(const float4*)(wrb + k);
            float4 xv0 = *(const float4*)(x0 + k);
            float4 xv1 = *(const float4*)(x1 + k);
            a0 = fma((double)xv0.x, (double)wv.x, a0);
            a1 = fma((double)xv1.x, (double)wv.x, a1);
            a0 = fma((double)xv0.y, (double)wv.y, a0);
            a1 = fma((double)xv1.y, (double)wv.y, a1);
            a0 = fma((double)xv0.z, (double)wv.z, a0);
            a1 = fma((double)xv1.z, (double)wv.z, a1);
            a0 = fma((double)xv0.w, (double)wv.w, a0);
            a1 = fma((double)xv1.w, (double)wv.w, a1);
        }
        sRed[t * 2]     = a0;
        sRed[t * 2 + 1] = a1;
        __syncthreads();
        if (t < 128) {
            #pragma unroll
            for (int i = 0; i < 2; ++i)
                sRed[t * 2 + i] = sRed[t * 2 + i] + sRed[(t + 128) * 2 + i]
                                + sRed[(t + 256) * 2 + i] + sRed[(t + 384) * 2 + i];
        }
        __syncthreads();

        if (t < 64) {
            const int lane = t;
            const double bgl = (double)bg[lane];
            #pragma unroll 1
            for (int i = 0; i < 2; ++i) {
                const int row = i ? r1 : r0;
                double g = sRed[lane * 2 + i];
                double n = sRed[(64 + lane) * 2 + i];
                double lgd = g + bgl;
                double nz = (double)noise[(size_t)row * NE + lane];
                double vcur = fma(nz, softplus_d(n), lgd);

                double tkv[TOPK]; int tki[TOPK];
                #pragma unroll
                for (int k = 0; k < TOPK; ++k) {
                    double mv = vcur; int mi = lane;
                    #pragma unroll
                    for (int o = 32; o > 0; o >>= 1) {
                        double ov = __shfl_xor(mv, o);
                        int    oi = __shfl_xor(mi, o);
                        if (ov > mv || (ov == mv && oi < mi)) { mv = ov; mi = oi; }
                    }
                    tkv[k] = mv; tki[k] = mi;
                    if (lane == mi) vcur = -1e300;
                }
                double m0 = tkv[0], s = 0.0, wk[TOPK];
                #pragma unroll
                for (int k = 0; k < TOPK; ++k) { wk[k] = exp(tkv[k] - m0); s += wk[k]; }
                double inv = 1.0 / s;
                float myw = 0.f; int myi = 0;
                #pragma unroll
                for (int k = 0; k < TOPK; ++k)
                    if (lane == k) { myw = (float)(wk[k] * inv); myi = tki[k]; }
                if (lane < TOPK) {
                    out_w[(size_t)row * TOPK + lane] = myw;
                    out_i[(size_t)row * TOPK + lane] = (float)myi;
                }
            }
        }
        __syncthreads();
    }
}

extern "C" void kernel_launch(void* const* d_in, const int* in_sizes, int n_in,
                              void* d_out, int out_size, void* d_ws, size_t ws_size,
                              hipStream_t stream) {
    const float* x     = (const float*)d_in[0];
    const float* noise = (const float*)d_in[1];
    const float* Wg    = (const float*)d_in[2];
    const float* bg    = (const float*)d_in[3];
    const float* Wn    = (const float*)d_in[4];
    float* out = (float*)d_out;
    float* ws  = (float*)d_ws;
    char*  wsW = (char*)d_ws + WSPLIT_BYTE;

    long cap = (long)(ws_size / 4) - WS_LIST;
    int listCap = (int)(cap < 0 ? 0 : (cap > NB ? NB : cap));
    const bool pre   = ws_size >= (size_t)WSPLIT_REQ;
    const bool split = ws_size >= (size_t)SPLIT_REQ;

    if (split) {
        float* part0 = (float*)((char*)d_ws + PART0_BYTE);
        float* part1 = (float*)((char*)d_ws + PART1_BYTE);
        hipLaunchKernelGGL(prep_kernel, dim3(129), dim3(256), 0, stream, Wg, Wn, wsW, ws);
        hipLaunchKernelGGL(gemm_half_kernel, dim3(2 * NB / BM), dim3(512), 0, stream,
                           x, wsW, part0, part1);
        hipLaunchKernelGGL(gating_kernel, dim3(NB / 128), dim3(512), 0, stream,
                           part0, part1, noise, bg,
                           out, out + (size_t)NB * TOPK, ws, listCap);
    } else if (pre) {
        hipLaunchKernelGGL(prep_kernel, dim3(129), dim3(256), 0, stream, Wg, Wn, wsW, ws);
        hipLaunchKernelGGL(gate_main_kernel<true>, dim3(NB / BM), dim3(512), 0, stream,
                           x, noise, Wg, bg, Wn, wsW,
                           out, out + (size_t)NB * TOPK, ws, listCap);
    } else {
        hipLaunchKernelGGL(init_ws_kernel, dim3(1), dim3(256), 0, stream, ws);
        hipLaunchKernelGGL(gate_main_kernel<false>, dim3(NB / BM), dim3(512), 0, stream,
                           x, noise, Wg, bg, Wn, wsW,
                           out, out + (size_t)NB * TOPK, ws, listCap);
    }
    hipLaunchKernelGGL(recheck_finalize_kernel, dim3(1024), dim3(512), 0, stream,
                       x, noise, Wg, bg, Wn,
                       out, out + (size_t)NB * TOPK, out + 2 * (size_t)NB * TOPK,
                       ws, listCap);
}

// Round 20
// 144.803 us; speedup vs baseline: 1.7266x; 1.4402x over previous
//
#include <hip/hip_runtime.h>
#include <math.h>

#define IDIM 2048
#define NE   64
#define TOPK 8
#define NB   16384
#define BM   32            // rows per block
#define BK   64            // k per chunk
#define NCH  (IDIM / BK)   // 32 chunks (monolithic path)
#define KH   1024          // K half (split path)
#define NCHH 16            // tiles per half
#define TAU  2.5e-4f

// ws float layout: [0..63] f counts, [64..127] p sums, [128] z sum,
//                  [129] (int) flag count, [130..130+NB) (int) flagged row list
// byte WSPLIT_BYTE..: pre-split W tiles (32 tiles x (16KB hi + 16KB lo))
// byte PART0/PART1: fp32 partial logits [NB][128] per K-half (split path)
#define WS_CNT 129
#define WS_LIST 130
#define WSPLIT_BYTE 66560
#define WSPLIT_REQ  (WSPLIT_BYTE + NCH * 32768)
#define PART0_BYTE  (WSPLIT_BYTE + NCH * 32768)
#define PART1_BYTE  (PART0_BYTE + (size_t)NB * 128 * 4)
#define SPLIT_REQ   (PART1_BYTE + (size_t)NB * 128 * 4)

typedef __attribute__((ext_vector_type(8))) short bf16x8_t;  // 8 bf16 = 4 VGPRs
typedef __attribute__((ext_vector_type(4))) float f32x4_t;   // MFMA acc

__device__ __forceinline__ float softplusf(float v) {
    return (v > 0.f) ? (v + log1pf(expf(-v))) : log1pf(expf(v));
}
__device__ __forceinline__ double softplus_d(double v) {
    return (v > 0.0) ? (v + log1p(exp(-v))) : log1p(exp(v));
}

// deterministic RNE fp32 -> bf16 bits
__device__ __forceinline__ short f2bf(float f) {
    unsigned u = __float_as_uint(f);
    unsigned r = (u + 0x7FFFu + ((u >> 16) & 1u)) >> 16;
    return (short)r;
}
__device__ __forceinline__ float bf2f(short s) {
    return __uint_as_float(((unsigned)(unsigned short)s) << 16);
}

__global__ void init_ws_kernel(float* ws) {
    int t = threadIdx.x;
    if (t < WS_LIST) ws[t] = 0.0f;
}

__device__ __forceinline__ void split8(const float4 v0, const float4 v1,
                                       bf16x8_t& H, bf16x8_t& L) {
    float fv[8] = {v0.x, v0.y, v0.z, v0.w, v1.x, v1.y, v1.z, v1.w};
    #pragma unroll
    for (int q = 0; q < 8; ++q) {
        short hb = f2bf(fv[q]);
        short lb = f2bf(fv[q] - bf2f(hb));
        H[q] = hb; L[q] = lb;
    }
}

__device__ __forceinline__ void cvt_slot(const float4 v0, const float4 v1,
                                         char* hiP, char* loP, int off) {
    bf16x8_t H, L;
    split8(v0, v1, H, L);
    *(bf16x8_t*)(hiP + off) = H;
    *(bf16x8_t*)(loP + off) = L;
}

// ---------------- pass 0: init ws + pre-split W into swizzled LDS tile images ----------------
__global__ __launch_bounds__(256) void prep_kernel(
    const float* __restrict__ Wg, const float* __restrict__ Wn,
    char* __restrict__ wsW, float* __restrict__ ws)
{
    if (blockIdx.x == 128) {             // merged init
        if (threadIdx.x < WS_LIST) ws[threadIdx.x] = 0.0f;
        return;
    }
    int g = blockIdx.x * 256 + threadIdx.x;   // 0..32767
    int t = g >> 10, i = g & 1023;
    int row = i >> 3, wslot = i & 7;
    int kslot = wslot ^ (row & 7);
    const float* src = (row < 64 ? Wg + (size_t)row * IDIM
                                 : Wn + (size_t)(row - 64) * IDIM) + t * BK + kslot * 8;
    float4 v0 = *(const float4*)src;
    float4 v1 = *(const float4*)(src + 4);
    bf16x8_t H, L;
    split8(v0, v1, H, L);
    char* dst = wsW + (size_t)t * 32768;
    *(bf16x8_t*)(dst + i * 16)         = H;
    *(bf16x8_t*)(dst + 16384 + i * 16) = L;
}

// ---------------- pass 1a (split): half-K GEMM -> fp32 partials ----------------
// LDS exactly 40960B -> 4 blocks/CU: AH@0 AL@4096 BH@8192 BL@24576
__global__ __launch_bounds__(512, 4) void gemm_half_kernel(
    const float* __restrict__ x, const char* __restrict__ wsW,
    float* __restrict__ part0, float* __restrict__ part1)
{
    __shared__ char smem[40960] __attribute__((aligned(16)));
    char* AH = smem;
    char* AL = smem + 4096;
    char* BH = smem + 8192;
    char* BL = smem + 24576;

    const int u   = threadIdx.x;
    const int w   = u >> 6;
    const int l   = u & 63;
    const int lr  = l & 15;
    const int lg4 = l >> 4;
    const int s7  = lr & 7;
    const int half = blockIdx.x & 1;
    const int row0 = (blockIdx.x >> 1) * BM;
    float* pb = half ? part1 : part0;

    const int ar  = (u >> 3) & 31;
    const int ac  = u & 7;
    const int aoff = ar * 128 + (((ac ^ (ar & 7)) & 7) << 4);
    const float* pa = x + (size_t)(row0 + ar) * IDIM + half * KH + ac * 8;

    f32x4_t acc[2];
    #pragma unroll
    for (int mt = 0; mt < 2; ++mt) {
        f32x4_t z = {0.f, 0.f, 0.f, 0.f};
        acc[mt] = z;
    }

    float4 ra0, ra1;
    int4 w0, w1, w2, w3;

#define HLOADT(tt) { const int k0 = (tt) * BK;                                  \
    if (u < 256) { ra0 = *(const float4*)(pa + k0);                             \
                   ra1 = *(const float4*)(pa + k0 + 4); }                       \
    const char* s_ = wsW + (size_t)(half * NCHH + (tt)) * 32768 + u * 16;       \
    w0 = *(const int4*)(s_);          w1 = *(const int4*)(s_ + 8192);           \
    w2 = *(const int4*)(s_ + 16384);  w3 = *(const int4*)(s_ + 24576); }

    HLOADT(0);

    for (int t = 0; t < NCHH; ++t) {
        __syncthreads();
        if (u < 256) cvt_slot(ra0, ra1, AH, AL, aoff);
        *(int4*)(BH + u * 16)        = w0;
        *(int4*)(BH + 8192 + u * 16) = w1;
        *(int4*)(BL + u * 16)        = w2;
        *(int4*)(BL + 8192 + u * 16) = w3;
        if (t + 1 < NCHH) HLOADT(t + 1);
        __syncthreads();

        #pragma unroll
        for (int ks = 0; ks < 2; ++ks) {
            const int so = (((ks * 4 + lg4) ^ s7) << 4);
            bf16x8_t ah[2], al_[2], bh, bl;
            #pragma unroll
            for (int mt = 0; mt < 2; ++mt) {
                const int o = (mt * 16 + lr) * 128 + so;
                ah[mt]  = *(const bf16x8_t*)(AH + o);
                al_[mt] = *(const bf16x8_t*)(AL + o);
            }
            {
                const int o = (w * 16 + lr) * 128 + so;
                bh = *(const bf16x8_t*)(BH + o);
                bl = *(const bf16x8_t*)(BL + o);
            }
            #pragma unroll
            for (int mt = 0; mt < 2; ++mt) {
                acc[mt] = __builtin_amdgcn_mfma_f32_16x16x32_bf16(ah[mt],  bh, acc[mt], 0, 0, 0);
                acc[mt] = __builtin_amdgcn_mfma_f32_16x16x32_bf16(ah[mt],  bl, acc[mt], 0, 0, 0);
                acc[mt] = __builtin_amdgcn_mfma_f32_16x16x32_bf16(al_[mt], bh, acc[mt], 0, 0, 0);
            }
        }
    }

    // ---- store partials (C/D: col=lane&15, row=(lane>>4)*4+reg) ----
    #pragma unroll
    for (int mt = 0; mt < 2; ++mt)
        #pragma unroll
        for (int r = 0; r < 4; ++r)
            pb[(size_t)(row0 + mt * 16 + lg4 * 4 + r) * 128 + (w * 16 + lr)] = acc[mt][r];
}

// ---------------- pass 1b (split): gating from partials (R16 epilogue geometry) ----------------
// 512 blocks x 32 rows; 8 waves x 4 rows -> 4096 waves (4/SIMD) for shfl latency hiding.
__global__ __launch_bounds__(512) void gating_kernel(
    const float* __restrict__ part0, const float* __restrict__ part1,
    const float* __restrict__ noise, const float* __restrict__ bg,
    float* __restrict__ out_w, float* __restrict__ out_i,
    float* __restrict__ ws, int listCap)
{
    __shared__ float sP[NE];
    __shared__ float sF[NE];
    __shared__ float sZ[1];
    const int u = threadIdx.x;
    const int w = u >> 6, l = u & 63;
    const int row0 = blockIdx.x * 32;

    if (u < NE) { sP[u] = 0.f; sF[u] = 0.f; }
    if (u == 0) sZ[0] = 0.f;
    __syncthreads();

    float pacc = 0.f, zacc = 0.f;
    #pragma unroll 1
    for (int rr = 0; rr < 4; ++rr) {
        const int grow = row0 + w * 4 + rr;
        float lg   = part0[(size_t)grow * 128 + l] + part1[(size_t)grow * 128 + l] + bg[l];
        float npre = part0[(size_t)grow * 128 + 64 + l] + part1[(size_t)grow * 128 + 64 + l];
        float vcur = fmaf(noise[(size_t)grow * NE + l], softplusf(npre), lg);

        float tkv[9]; int tki[9];
        #pragma unroll
        for (int k = 0; k < 9; ++k) {
            float mv = vcur; int mi = l;
            #pragma unroll
            for (int o = 32; o > 0; o >>= 1) {
                float ov = __shfl_xor(mv, o);
                int   oi = __shfl_xor(mi, o);
                if (ov > mv || (ov == mv && oi < mi)) { mv = ov; mi = oi; }
            }
            tkv[k] = mv; tki[k] = mi;
            if (l == mi) vcur = -1e30f;
        }

        float m0 = tkv[0], s = 0.f, wk[TOPK];
        #pragma unroll
        for (int k = 0; k < TOPK; ++k) { wk[k] = expf(tkv[k] - m0); s += wk[k]; }
        float inv = 1.f / s;
        float myw = 0.f; int myi = 0;
        #pragma unroll
        for (int k = 0; k < TOPK; ++k)
            if (l == k) { myw = wk[k] * inv; myi = tki[k]; }
        if (l < TOPK) {
            out_w[(size_t)grow * TOPK + l] = myw;
            out_i[(size_t)grow * TOPK + l] = (float)myi;
        }

        if (l == 0) {
            atomicAdd(&sF[tki[0]], 1.f);
            float ming = 1e30f;
            #pragma unroll
            for (int k = 0; k < 8; ++k) ming = fminf(ming, tkv[k] - tkv[k + 1]);
            if (ming < TAU) {
                int slot = atomicAdd((int*)&ws[WS_CNT], 1);
                if (slot < listCap) ((int*)ws)[WS_LIST + slot] = grow;
            }
        }

        float rm = lg;
        #pragma unroll
        for (int o = 32; o > 0; o >>= 1) rm = fmaxf(rm, __shfl_xor(rm, o));
        float pe = expf(lg - rm);
        float ssum = pe;
        #pragma unroll
        for (int o = 32; o > 0; o >>= 1) ssum += __shfl_xor(ssum, o);
        pacc += pe / ssum;
        if (l == 0) { float lse = rm + logf(ssum); zacc += lse * lse; }
    }

    atomicAdd(&sP[l], pacc);
    if (l == 0) atomicAdd(sZ, zacc);
    __syncthreads();
    if (u < NE) {
        atomicAdd(&ws[u],      sF[u]);
        atomicAdd(&ws[NE + u], sP[u]);
    }
    if (u == 0) atomicAdd(&ws[2 * NE], sZ[0]);
}

// ---------------- pass 1 (fallback): R16 monolithic GEMM + gating ----------------
template<bool PRE>
__global__ __launch_bounds__(512, 4) void gate_main_kernel(
    const float* __restrict__ x, const float* __restrict__ noise,
    const float* __restrict__ Wg, const float* __restrict__ bg,
    const float* __restrict__ Wn, const char* __restrict__ wsW,
    float* __restrict__ out_w, float* __restrict__ out_i,
    float* __restrict__ ws, int listCap)
{
    __shared__ char smem[41488] __attribute__((aligned(16)));
    char* AH = smem;
    char* AL = smem + 4096;
    char* BH = smem + 8192;
    char* BL = smem + 24576;
    float* sP = (float*)(smem + 40960);
    float* sF = (float*)(smem + 41216);
    float* sZ = (float*)(smem + 41472);
    float* sL = (float*)smem;

    const int u   = threadIdx.x;
    const int w   = u >> 6;
    const int l   = u & 63;
    const int lr  = l & 15;
    const int lg4 = l >> 4;
    const int s7  = lr & 7;
    const int row0 = blockIdx.x * BM;

    if (u < NE) { sP[u] = 0.f; sF[u] = 0.f; }
    if (u == 0) sZ[0] = 0.f;

    const int ar  = (u >> 3) & 31;
    const int ac  = u & 7;
    const int aoff = ar * 128 + (((ac ^ (ar & 7)) & 7) << 4);
    const float* pa = x + (size_t)(row0 + ar) * IDIM + ac * 8;

    const int br  = u >> 3;
    const float* pg = Wg + (size_t)br * IDIM + ac * 8;
    const float* pn = Wn + (size_t)br * IDIM + ac * 8;
    const int woff = br * 128 + ((ac ^ (br & 7)) << 4);

    f32x4_t acc[2];
    #pragma unroll
    for (int mt = 0; mt < 2; ++mt) {
        f32x4_t z = {0.f, 0.f, 0.f, 0.f};
        acc[mt] = z;
    }

    float4 ra0, ra1;
    int4 w0, w1, w2, w3;
    float4 g0, g1, n0, n1;

#define LOADT(tt) { const int k0 = (tt) * BK;                                   \
    if (u < 256) { ra0 = *(const float4*)(pa + k0);                             \
                   ra1 = *(const float4*)(pa + k0 + 4); }                       \
    if constexpr (PRE) {                                                        \
        const char* s_ = wsW + (size_t)(tt) * 32768 + u * 16;                   \
        w0 = *(const int4*)(s_);          w1 = *(const int4*)(s_ + 8192);       \
        w2 = *(const int4*)(s_ + 16384);  w3 = *(const int4*)(s_ + 24576);      \
    } else {                                                                    \
        g0 = *(const float4*)(pg + k0);   g1 = *(const float4*)(pg + k0 + 4);   \
        n0 = *(const float4*)(pn + k0);   n1 = *(const float4*)(pn + k0 + 4);   \
    } }

    LOADT(0);

    for (int t = 0; t < NCH; ++t) {
        __syncthreads();
        if (u < 256) cvt_slot(ra0, ra1, AH, AL, aoff);
        if constexpr (PRE) {
            *(int4*)(BH + u * 16)        = w0;
            *(int4*)(BH + 8192 + u * 16) = w1;
            *(int4*)(BL + u * 16)        = w2;
            *(int4*)(BL + 8192 + u * 16) = w3;
        } else {
            cvt_slot(g0, g1, BH, BL, woff);
            cvt_slot(n0, n1, BH, BL, woff + 8192);
        }
        if (t + 1 < NCH) LOADT(t + 1);
        __syncthreads();

        #pragma unroll
        for (int ks = 0; ks < 2; ++ks) {
            const int so = (((ks * 4 + lg4) ^ s7) << 4);
            bf16x8_t ah[2], al_[2], bh, bl;
            #pragma unroll
            for (int mt = 0; mt < 2; ++mt) {
                const int o = (mt * 16 + lr) * 128 + so;
                ah[mt]  = *(const bf16x8_t*)(AH + o);
                al_[mt] = *(const bf16x8_t*)(AL + o);
            }
            {
                const int o = (w * 16 + lr) * 128 + so;
                bh = *(const bf16x8_t*)(BH + o);
                bl = *(const bf16x8_t*)(BL + o);
            }
            #pragma unroll
            for (int mt = 0; mt < 2; ++mt) {
                acc[mt] = __builtin_amdgcn_mfma_f32_16x16x32_bf16(ah[mt],  bh, acc[mt], 0, 0, 0);
                acc[mt] = __builtin_amdgcn_mfma_f32_16x16x32_bf16(ah[mt],  bl, acc[mt], 0, 0, 0);
                acc[mt] = __builtin_amdgcn_mfma_f32_16x16x32_bf16(al_[mt], bh, acc[mt], 0, 0, 0);
            }
        }
    }
    __syncthreads();

    #pragma unroll
    for (int mt = 0; mt < 2; ++mt)
        #pragma unroll
        for (int r = 0; r < 4; ++r)
            sL[(mt * 16 + lg4 * 4 + r) * 132 + (w * 16 + lr)] = acc[mt][r];
    __syncthreads();

    float pacc = 0.f, zacc = 0.f;
    #pragma unroll 1
    for (int rr = 0; rr < 4; ++rr) {
        const int r = w * 4 + rr;
        const int grow = row0 + r;
        float lg   = sL[r * 132 + l] + bg[l];
        float npre = sL[r * 132 + 64 + l];
        float vcur = fmaf(noise[(size_t)grow * NE + l], softplusf(npre), lg);

        float tkv[9]; int tki[9];
        #pragma unroll
        for (int k = 0; k < 9; ++k) {
            float mv = vcur; int mi = l;
            #pragma unroll
            for (int o = 32; o > 0; o >>= 1) {
                float ov = __shfl_xor(mv, o);
                int   oi = __shfl_xor(mi, o);
                if (ov > mv || (ov == mv && oi < mi)) { mv = ov; mi = oi; }
            }
            tkv[k] = mv; tki[k] = mi;
            if (l == mi) vcur = -1e30f;
        }

        float m0 = tkv[0], s = 0.f, wk[TOPK];
        #pragma unroll
        for (int k = 0; k < TOPK; ++k) { wk[k] = expf(tkv[k] - m0); s += wk[k]; }
        float inv = 1.f / s;
        float myw = 0.f; int myi = 0;
        #pragma unroll
        for (int k = 0; k < TOPK; ++k)
            if (l == k) { myw = wk[k] * inv; myi = tki[k]; }
        if (l < TOPK) {
            out_w[(size_t)grow * TOPK + l] = myw;
            out_i[(size_t)grow * TOPK + l] = (float)myi;
        }

        if (l == 0) {
            atomicAdd(&sF[tki[0]], 1.f);
            float ming = 1e30f;
            #pragma unroll
            for (int k = 0; k < 8; ++k) ming = fminf(ming, tkv[k] - tkv[k + 1]);
            if (ming < TAU) {
                int slot = atomicAdd((int*)&ws[WS_CNT], 1);
                if (slot < listCap) ((int*)ws)[WS_LIST + slot] = grow;
            }
        }

        float rm = lg;
        #pragma unroll
        for (int o = 32; o > 0; o >>= 1) rm = fmaxf(rm, __shfl_xor(rm, o));
        float pe = expf(lg - rm);
        float ssum = pe;
        #pragma unroll
        for (int o = 32; o > 0; o >>= 1) ssum += __shfl_xor(ssum, o);
        pacc += pe / ssum;
        if (l == 0) { float lse = rm + logf(ssum); zacc += lse * lse; }
    }

    atomicAdd(&sP[l], pacc);
    if (l == 0) atomicAdd(sZ, zacc);
    __syncthreads();
    if (u < NE) {
        atomicAdd(&ws[u],      sF[u]);
        atomicAdd(&ws[NE + u], sP[u]);
    }
    if (u == 0) atomicAdd(&ws[2 * NE], sZ[0]);
}

// ---------------- pass 2: finalize scalars (block 0) + fp64 recheck, 2 rows/block ----------------
__global__ __launch_bounds__(512) void recheck_finalize_kernel(
    const float* __restrict__ x, const float* __restrict__ noise,
    const float* __restrict__ Wg, const float* __restrict__ bg,
    const float* __restrict__ Wn,
    float* __restrict__ out_w, float* __restrict__ out_i, float* __restrict__ out_s,
    const float* __restrict__ ws, int listCap)
{
    __shared__ double sRed[1024];
    const int t = threadIdx.x;

    if (blockIdx.x == 0 && t < 64) {
        float v = (ws[t] / (float)NB) * (ws[NE + t] / (float)NB);
        #pragma unroll
        for (int o = 32; o > 0; o >>= 1) v += __shfl_down(v, o);
        if (t == 0) {
            out_s[0] = (float)NE * v;
            out_s[1] = ws[2 * NE] / (float)NB;
        }
    }

    const int* wsi = (const int*)ws;
    int cnt = wsi[WS_CNT];
    if (cnt > listCap) cnt = listCap;
    if (cnt <= 0) return;

    const int slot = t & 127;
    const int q4   = t >> 7;
    const float* wrb = ((slot < 64) ? (Wg + (size_t)slot * IDIM)
                                    : (Wn + (size_t)(slot - 64) * IDIM)) + q4 * 512;

    const int npair = (cnt + 1) >> 1;
    for (int bi = blockIdx.x; bi < npair; bi += gridDim.x) {
        const int i1 = 2 * bi + 1;
        const int r0 = wsi[WS_LIST + 2 * bi];
        const int r1 = wsi[WS_LIST + (i1 < cnt ? i1 : cnt - 1)];
        const float* x0 = x + (size_t)r0 * IDIM + q4 * 512;
        const float* x1 = x + (size_t)r1 * IDIM + q4 * 512;

        double a0 = 0.0, a1 = 0.0;
        #pragma unroll 4
        for (int k = 0; k < 512; k += 4) {
            float4 wv  = *(const float4*)(wrb + k);
            float4 xv0 = *(const float4*)(x0 + k);
            float4 xv1 = *(const float4*)(x1 + k);
            a0 = fma((double)xv0.x, (double)wv.x, a0);
            a1 = fma((double)xv1.x, (double)wv.x, a1);
            a0 = fma((double)xv0.y, (double)wv.y, a0);
            a1 = fma((double)xv1.y, (double)wv.y, a1);
            a0 = fma((double)xv0.z, (double)wv.z, a0);
            a1 = fma((double)xv1.z, (double)wv.z, a1);
            a0 = fma((double)xv0.w, (double)wv.w, a0);
            a1 = fma((double)xv1.w, (double)wv.w, a1);
        }
        sRed[t * 2]     = a0;
        sRed[t * 2 + 1] = a1;
        __syncthreads();
        if (t < 128) {
            #pragma unroll
            for (int i = 0; i < 2; ++i)
                sRed[t * 2 + i] = sRed[t * 2 + i] + sRed[(t + 128) * 2 + i]
                                + sRed[(t + 256) * 2 + i] + sRed[(t + 384) * 2 + i];
        }
        __syncthreads();

        if (t < 64) {
            const int lane = t;
            const double bgl = (double)bg[lane];
            #pragma unroll 1
            for (int i = 0; i < 2; ++i) {
                const int row = i ? r1 : r0;
                double g = sRed[lane * 2 + i];
                double n = sRed[(64 + lane) * 2 + i];
                double lgd = g + bgl;
                double nz = (double)noise[(size_t)row * NE + lane];
                double vcur = fma(nz, softplus_d(n), lgd);

                double tkv[TOPK]; int tki[TOPK];
                #pragma unroll
                for (int k = 0; k < TOPK; ++k) {
                    double mv = vcur; int mi = lane;
                    #pragma unroll
                    for (int o = 32; o > 0; o >>= 1) {
                        double ov = __shfl_xor(mv, o);
                        int    oi = __shfl_xor(mi, o);
                        if (ov > mv || (ov == mv && oi < mi)) { mv = ov; mi = oi; }
                    }
                    tkv[k] = mv; tki[k] = mi;
                    if (lane == mi) vcur = -1e300;
                }
                double m0 = tkv[0], s = 0.0, wk[TOPK];
                #pragma unroll
                for (int k = 0; k < TOPK; ++k) { wk[k] = exp(tkv[k] - m0); s += wk[k]; }
                double inv = 1.0 / s;
                float myw = 0.f; int myi = 0;
                #pragma unroll
                for (int k = 0; k < TOPK; ++k)
                    if (lane == k) { myw = (float)(wk[k] * inv); myi = tki[k]; }
                if (lane < TOPK) {
                    out_w[(size_t)row * TOPK + lane] = myw;
                    out_i[(size_t)row * TOPK + lane] = (float)myi;
                }
            }
        }
        __syncthreads();
    }
}

extern "C" void kernel_launch(void* const* d_in, const int* in_sizes, int n_in,
                              void* d_out, int out_size, void* d_ws, size_t ws_size,
                              hipStream_t stream) {
    const float* x     = (const float*)d_in[0];
    const float* noise = (const float*)d_in[1];
    const float* Wg    = (const float*)d_in[2];
    const float* bg    = (const float*)d_in[3];
    const float* Wn    = (const float*)d_in[4];
    float* out = (float*)d_out;
    float* ws  = (float*)d_ws;
    char*  wsW = (char*)d_ws + WSPLIT_BYTE;

    long cap = (long)(ws_size / 4) - WS_LIST;
    int listCap = (int)(cap < 0 ? 0 : (cap > NB ? NB : cap));
    const bool pre   = ws_size >= (size_t)WSPLIT_REQ;
    const bool split = ws_size >= (size_t)SPLIT_REQ;

    if (split) {
        float* part0 = (float*)((char*)d_ws + PART0_BYTE);
        float* part1 = (float*)((char*)d_ws + PART1_BYTE);
        hipLaunchKernelGGL(prep_kernel, dim3(129), dim3(256), 0, stream, Wg, Wn, wsW, ws);
        hipLaunchKernelGGL(gemm_half_kernel, dim3(2 * NB / BM), dim3(512), 0, stream,
                           x, wsW, part0, part1);
        hipLaunchKernelGGL(gating_kernel, dim3(NB / 32), dim3(512), 0, stream,
                           part0, part1, noise, bg,
                           out, out + (size_t)NB * TOPK, ws, listCap);
    } else if (pre) {
        hipLaunchKernelGGL(prep_kernel, dim3(129), dim3(256), 0, stream, Wg, Wn, wsW, ws);
        hipLaunchKernelGGL(gate_main_kernel<true>, dim3(NB / BM), dim3(512), 0, stream,
                           x, noise, Wg, bg, Wn, wsW,
                           out, out + (size_t)NB * TOPK, ws, listCap);
    } else {
        hipLaunchKernelGGL(init_ws_kernel, dim3(1), dim3(256), 0, stream, ws);
        hipLaunchKernelGGL(gate_main_kernel<false>, dim3(NB / BM), dim3(512), 0, stream,
                           x, noise, Wg, bg, Wn, wsW,
                           out, out + (size_t)NB * TOPK, ws, listCap);
    }
    hipLaunchKernelGGL(recheck_finalize_kernel, dim3(1024), dim3(512), 0, stream,
                       x, noise, Wg, bg, Wn,
                       out, out + (size_t)NB * TOPK, out + 2 * (size_t)NB * TOPK,
                       ws, listCap);
}